// Round 23
// baseline (148.381 us; speedup 1.0000x reference)
//
#include <hip/hip_runtime.h>

typedef _Float16 f16;
typedef _Float16 f16x4 __attribute__((ext_vector_type(4)));
typedef _Float16 f16x8 __attribute__((ext_vector_type(8)));
typedef float f32x4 __attribute__((ext_vector_type(4)));
typedef float f32x16 __attribute__((ext_vector_type(16)));

// async global->LDS, 16B per lane; LDS dest = wave-uniform base + lane*16
#define LOADLDS16(gp, lp)                                                     \
  __builtin_amdgcn_global_load_lds(                                           \
      (const __attribute__((address_space(1))) void*)(gp),                    \
      (__attribute__((address_space(3))) void*)(lp), 16, 0, 0)

// ---------------------------------------------------------------------------
// Merged prep: blocks 0-8191 cast activations f32->f16 (float4 vectorized);
// blocks 8192-9215 cast+transpose the 4 weight matrices (64x64 LDS tiles).
// ---------------------------------------------------------------------------
__global__ __launch_bounds__(256) void k_prep(
    const float* __restrict__ xa, const float* __restrict__ xb,
    f16* __restrict__ ya, f16* __restrict__ yb, const float* __restrict__ w0,
    const float* __restrict__ w1, const float* __restrict__ w2,
    const float* __restrict__ w3, f16* __restrict__ o0, f16* __restrict__ o1,
    f16* __restrict__ o2, f16* __restrict__ o3) {
  __shared__ f16 T[64][72];
  const int tid = threadIdx.x;
  const int bid = blockIdx.x;
  if (bid < 8192) {
    int i = bid * 256 + tid;
    const float* x;
    f16* y;
    if (i < 1048576) {
      x = xa; y = ya;
    } else {
      x = xb; y = yb; i -= 1048576;
    }
    float4 v = reinterpret_cast<const float4*>(x)[i];
    f16x4 o;
    o[0] = (f16)v.x; o[1] = (f16)v.y; o[2] = (f16)v.z; o[3] = (f16)v.w;
    reinterpret_cast<f16x4*>(y)[i] = o;
    return;
  }
  const int bid2 = bid - 8192;
  const int z = bid2 >> 8, yb_ = (bid2 >> 4) & 15, xb_ = bid2 & 15;
  const float* W;
  f16* O;
  switch (z) {
    case 0: W = w0; O = o0; break;
    case 1: W = w1; O = o1; break;
    case 2: W = w2; O = o2; break;
    default: W = w3; O = o3; break;
  }
  const int r0 = yb_ * 64, c0 = xb_ * 64;
#pragma unroll
  for (int i = 0; i < 4; ++i) {
    int c = i * 256 + tid;
    int row = c >> 4, col = (c & 15) * 4;
    float4 v = *reinterpret_cast<const float4*>(W + (size_t)(r0 + row) * 1024 + c0 + col);
    T[col + 0][row] = (f16)v.x;
    T[col + 1][row] = (f16)v.y;
    T[col + 2][row] = (f16)v.z;
    T[col + 3][row] = (f16)v.w;
  }
  __syncthreads();
#pragma unroll
  for (int i = 0; i < 2; ++i) {
    int c = i * 256 + tid;
    int cc = c >> 3, ro = (c & 7) * 8;
    f16x8 v;
#pragma unroll
    for (int j = 0; j < 8; ++j) v[j] = T[cc][ro + j];
    *reinterpret_cast<f16x8*>(O + (size_t)(c0 + cc) * 1024 + r0 + ro) = v;
  }
}

// ---------------------------------------------------------------------------
// Fused QKV projection (round-18 v18, frozen): swizzled grid, swapped-operand
// Q/K epilogue (f16x4 stores), V written transposed.
// ---------------------------------------------------------------------------
__global__ __launch_bounds__(256) void k_gemm_qkv(const f16* __restrict__ Xq,
                                                  const f16* __restrict__ Xkv,
                                                  const f16* __restrict__ Bt,
                                                  f16* __restrict__ outp) {
  __shared__ f16 As[128 * 64];  // 16 KB
  __shared__ f16 Bs[128 * 64];  // 16 KB
  const int tid = threadIdx.x;
  const int w = tid >> 6, l = tid & 63;
  const int lr = l & 15, lq = l >> 4;
  const int flat = blockIdx.y * 24 + blockIdx.x;
  const int ord = (flat & 7) * 96 + (flat >> 3);
  const int m0 = (ord / 24) * 128, n0 = (ord % 24) * 128;
  const f16* A = (n0 < 1024) ? Xq : Xkv;
  const int wr = (w >> 1) * 64, wc = (w & 1) * 64;
  const int K = 1024;
  const bool vplane = (n0 >= 2048);
  f32x4 acc[4][4] = {};
  for (int kt = 0; kt < K; kt += 64) {
#pragma unroll
    for (int i = 0; i < 4; ++i) {
      int c = (i * 4 + w) * 64 + l;
      LOADLDS16(A + (size_t)(m0 + (c >> 3)) * K + kt + (c & 7) * 8,
                As + (size_t)(i * 4 + w) * 512);
      LOADLDS16(Bt + (size_t)(n0 + (c >> 3)) * K + kt + (c & 7) * 8,
                Bs + (size_t)(i * 4 + w) * 512);
    }
    __syncthreads();
#pragma unroll
    for (int kk = 0; kk < 2; ++kk) {
      f16x8 af[4], bf[4];
#pragma unroll
      for (int m = 0; m < 4; ++m)
        af[m] = *reinterpret_cast<const f16x8*>(As + (wr + m * 16 + lr) * 64 + kk * 32 + lq * 8);
#pragma unroll
      for (int n = 0; n < 4; ++n)
        bf[n] = *reinterpret_cast<const f16x8*>(Bs + (wc + n * 16 + lr) * 64 + kk * 32 + lq * 8);
      if (vplane) {
#pragma unroll
        for (int m = 0; m < 4; ++m)
#pragma unroll
          for (int n = 0; n < 4; ++n)
            acc[m][n] = __builtin_amdgcn_mfma_f32_16x16x32_f16(af[m], bf[n], acc[m][n], 0, 0, 0);
      } else {
#pragma unroll
        for (int m = 0; m < 4; ++m)
#pragma unroll
          for (int n = 0; n < 4; ++n)
            acc[m][n] = __builtin_amdgcn_mfma_f32_16x16x32_f16(bf[n], af[m], acc[m][n], 0, 0, 0);
      }
    }
    __syncthreads();
  }
  if (vplane) {
#pragma unroll
    for (int m = 0; m < 4; ++m)
#pragma unroll
      for (int n = 0; n < 4; ++n) {
        int col = n0 + wc + n * 16 + lr;
        int row0 = m0 + wr + m * 16 + lq * 4;
        int b = row0 >> 10, s0 = row0 & 1023;
        int cc = col & 1023;
        int h = cc >> 6, dh = cc & 63;
        f16x4 v4;
#pragma unroll
        for (int r = 0; r < 4; ++r) v4[r] = (f16)acc[m][n][r];
        *reinterpret_cast<f16x4*>(
            outp + (size_t)2 * 4194304 +
            ((size_t)(b * 16 + h)) * 65536 + (size_t)dh * 1024 + s0) = v4;
      }
  } else {
#pragma unroll
    for (int m = 0; m < 4; ++m)
#pragma unroll
      for (int n = 0; n < 4; ++n) {
        int row0 = m0 + wr + m * 16 + lr;
        int col0 = n0 + wc + n * 16 + lq * 4;
        int b = row0 >> 10, sidx = row0 & 1023;
        int plane = col0 >> 10, cc = col0 & 1023;
        int h = cc >> 6, dh0 = cc & 63;
        f16x4 v4;
#pragma unroll
        for (int r = 0; r < 4; ++r) v4[r] = (f16)acc[m][n][r];
        *reinterpret_cast<f16x4*>(
            outp + (size_t)plane * 4194304 +
            (((size_t)(b * 16 + h)) * 1024 + sidx) * 64 + dh0) = v4;
      }
  }
}

// ---------------------------------------------------------------------------
// Output GEMM (round-18 v18, frozen): swizzled grid, BM=64 BN=128.
// ---------------------------------------------------------------------------
__global__ __launch_bounds__(256) void k_gemm_o(const f16* __restrict__ A,
                                                const f16* __restrict__ Bt,
                                                float* __restrict__ out, int M,
                                                int N, int K) {
  __shared__ f16 As[64 * 64];
  __shared__ f16 Bs[128 * 64];
  const int tid = threadIdx.x;
  const int w = tid >> 6, l = tid & 63;
  const int lr = l & 15, lq = l >> 4;
  const int flat = blockIdx.y * 8 + blockIdx.x;
  const int ord = (flat & 7) * 64 + (flat >> 3);
  const int m0 = (ord >> 3) * 64, n0 = (ord & 7) * 128;
  const int wr = (w >> 1) * 32, wc = (w & 1) * 64;
  f32x4 acc[2][4] = {};
  for (int kt = 0; kt < K; kt += 64) {
#pragma unroll
    for (int i = 0; i < 2; ++i) {
      int c = (i * 4 + w) * 64 + l;
      LOADLDS16(A + (size_t)(m0 + (c >> 3)) * K + kt + (c & 7) * 8,
                As + (size_t)(i * 4 + w) * 512);
    }
#pragma unroll
    for (int i = 0; i < 4; ++i) {
      int c = (i * 4 + w) * 64 + l;
      LOADLDS16(Bt + (size_t)(n0 + (c >> 3)) * K + kt + (c & 7) * 8,
                Bs + (size_t)(i * 4 + w) * 512);
    }
    __syncthreads();
#pragma unroll
    for (int kk = 0; kk < 2; ++kk) {
      f16x8 af[2], bf[4];
#pragma unroll
      for (int m = 0; m < 2; ++m)
        af[m] = *reinterpret_cast<const f16x8*>(As + (wr + m * 16 + lr) * 64 + kk * 32 + lq * 8);
#pragma unroll
      for (int n = 0; n < 4; ++n)
        bf[n] = *reinterpret_cast<const f16x8*>(Bs + (wc + n * 16 + lr) * 64 + kk * 32 + lq * 8);
#pragma unroll
      for (int m = 0; m < 2; ++m)
#pragma unroll
        for (int n = 0; n < 4; ++n)
          acc[m][n] = __builtin_amdgcn_mfma_f32_16x16x32_f16(af[m], bf[n], acc[m][n], 0, 0, 0);
    }
    __syncthreads();
  }
#pragma unroll
  for (int m = 0; m < 2; ++m)
#pragma unroll
    for (int n = 0; n < 4; ++n)
#pragma unroll
      for (int r = 0; r < 4; ++r) {
        int row = m0 + wr + m * 16 + lq * 4 + r;
        int col = n0 + wc + n * 16 + lr;
        out[(size_t)row * N + col] = acc[m][n][r];
      }
}

// ---------------------------------------------------------------------------
// Fused flash attention (T5), v22: v19 core (32x32x16, verified) with
// optional SPLIT-KV (flash-decoding). split=1: grid 1024, each block does 8
// KV-tiles (half) -> 4 blocks/CU = 16 waves/CU (2x TLP vs v19; occupancy was
// grid-capped at 2 blocks/CU through rounds 1-22). Partial O normalized to
// f16 + LSE f32; k_combine merges exactly. split=0: v19 byte-equivalent.
// ---------------------------------------------------------------------------
__global__ __launch_bounds__(256, 2) void k_attn(
    const f16* __restrict__ qb, const f16* __restrict__ kb,
    const f16* __restrict__ vtb, const float* __restrict__ bias,
    f16* __restrict__ ctx, f16* __restrict__ opart, float* __restrict__ lsebuf,
    int split) {
  const int bid = blockIdx.x;
  int h, b, qt, kvh;
  if (split) {
    const int ord = (bid & 7) * 128 + (bid >> 3);  // XCD-chunked
    h = ord >> 6; b = (ord >> 4) & 3; qt = (ord >> 1) & 7; kvh = ord & 1;
  } else {
    const int ord = (bid & 7) * 64 + (bid >> 3);
    h = ord >> 5; b = (ord >> 3) & 3; qt = ord & 7; kvh = 0;
  }
  const int nt = split ? 8 : 16;
  const int kvoff = kvh * 8;  // tile units (64 kv each)
  const int bh = b * 16 + h;
  const int q0 = qt * 128;
  const int tid = threadIdx.x, w = tid >> 6, l = tid & 63;
  const int l31 = l & 31, xi = l >> 5;
  const int qw = q0 + w * 32;

  __shared__ f16 Kb[2][4096];  // [kv=64][dh=64], granule swz g^(row&7)
  __shared__ f16 Vb[2][4096];  // [dh=64][kv=64], granule swz g^(row&7)

  // Q B-fragments: Q[q = qw + l31][dh = s*16 + xi*8 .. +7], s = 0..3
  const f16* qp = qb + ((size_t)bh * 1024 + qw + l31) * 64 + xi * 8;
  f16x8 qf[4];
#pragma unroll
  for (int s = 0; s < 4; ++s)
    qf[s] = *reinterpret_cast<const f16x8*>(qp + s * 16);

  f32x16 O[2] = {};
  float mrun = -3.0e38f, rsum = 0.f;  // per-lane; q-row = qw + l31

  const f16* kbase = kb + (size_t)bh * 65536;
  const f16* vbase = vtb + (size_t)bh * 65536;
  // bias: S[c][4g+e] needs bias[q][(kvoff+t)*64 + c*32 + 8g + 4*xi + e]
  const float* bq = bias + ((size_t)h * 1024 + qw + l31) * 1024 + 4 * xi;

  // DMA staging: 512 chunks of 16B per tile; gt = global tile index.
  auto stage = [&](int gt, int nxt) {
#pragma unroll
    for (int i = 0; i < 2; ++i) {
      int c = (i * 4 + w) * 64 + l;
      int row = c >> 3, g = (c & 7) ^ (row & 7);
      LOADLDS16(kbase + (size_t)(gt * 64 + row) * 64 + g * 8,
                &Kb[nxt][(i * 4 + w) * 512]);
      LOADLDS16(vbase + (size_t)row * 1024 + gt * 64 + g * 8,
                &Vb[nxt][(i * 4 + w) * 512]);
    }
  };

  stage(kvoff, 0);

#pragma unroll 1
  for (int t = 0; t < nt; ++t) {
    const int cur = t & 1;
    __builtin_amdgcn_s_barrier();
    // ---- bias loads FIRST (older than stage(t+1) in the VM queue) ----
    f32x4 bf[2][4];
#pragma unroll
    for (int c = 0; c < 2; ++c)
#pragma unroll
      for (int g = 0; g < 4; ++g)
        bf[c][g] = *reinterpret_cast<const f32x4*>(
            bq + (kvoff + t) * 64 + c * 32 + 8 * g);
    __builtin_amdgcn_sched_barrier(0);
    if (t < nt - 1) stage(kvoff + t + 1, cur ^ 1);
    __builtin_amdgcn_sched_barrier(0);
    // drain ONLY stage(t): outstanding = 4(stage t) + 8(bias) + 4(stage t+1)
    if (t < nt - 1) {
      asm volatile("s_waitcnt vmcnt(12)" ::: "memory");
    } else {
      asm volatile("s_waitcnt vmcnt(8)" ::: "memory");
    }
    __builtin_amdgcn_sched_barrier(0);

    // ---- S^T = K Q^T + bias  (S[c]: col q, rows kv = c*32 + pattern) ----
    f32x16 S[2];
#pragma unroll
    for (int c = 0; c < 2; ++c) {
#pragma unroll
      for (int g = 0; g < 4; ++g)
#pragma unroll
        for (int e = 0; e < 4; ++e) S[c][4 * g + e] = bf[c][g][e];
    }
    __builtin_amdgcn_s_setprio(1);
#pragma unroll
    for (int c = 0; c < 2; ++c) {
      int row = c * 32 + l31, s7 = l31 & 7;
      const f16* kbp = &Kb[cur][row * 64];
#pragma unroll
      for (int s = 0; s < 4; ++s) {
        f16x8 kf = *reinterpret_cast<const f16x8*>(kbp + (((2 * s + xi) ^ s7) * 8));
        S[c] = __builtin_amdgcn_mfma_f32_32x32x16_f16(kf, qf[s], S[c], 0, 0, 0);
      }
    }
    __builtin_amdgcn_s_setprio(0);

    // ---- defer-max (T13): all 32 S-values belong to one q-row ----
    float tmax = -3.0e38f;
#pragma unroll
    for (int c = 0; c < 2; ++c)
#pragma unroll
      for (int r = 0; r < 16; ++r) tmax = fmaxf(tmax, S[c][r]);
    if (!__all(tmax <= mrun + 8.0f)) {
      tmax = fmaxf(tmax, __shfl_xor(tmax, 32, 64));
      float mnew = fmaxf(mrun, tmax);
      float sc = __expf(mrun - mnew);  // identical in lanes l, l^32
      mrun = mnew;
      rsum *= sc;
#pragma unroll
      for (int d = 0; d < 2; ++d)
#pragma unroll
        for (int r = 0; r < 16; ++r) O[d][r] *= sc;
    }

    // ---- P = exp(S - m); per-lane rsum; pack quads ----
    f16x4 qd[2][4];
#pragma unroll
    for (int c = 0; c < 2; ++c)
#pragma unroll
      for (int g = 0; g < 4; ++g) {
        f32x4 p;
#pragma unroll
        for (int e = 0; e < 4; ++e) p[e] = __expf(S[c][4 * g + e] - mrun);
        rsum += (p[0] + p[1]) + (p[2] + p[3]);
        f16x4 ph = {(f16)p[0], (f16)p[1], (f16)p[2], (f16)p[3]};
        qd[c][g] = ph;
      }

    // ---- quad exchange with lane^32: build pb[u], u = 2c+v ----
    f16x8 pb[4];
#pragma unroll
    for (int c = 0; c < 2; ++c)
#pragma unroll
      for (int v = 0; v < 2; ++v) {
        union { f16x4 h; unsigned int u[2]; } snd, rcv;
        snd.h = xi ? qd[c][2 * v] : qd[c][2 * v + 1];
        rcv.u[0] = __shfl_xor(snd.u[0], 32, 64);
        rcv.u[1] = __shfl_xor(snd.u[1], 32, 64);
        f16x4 own = xi ? qd[c][2 * v + 1] : qd[c][2 * v];
        f16x4 q1 = xi ? rcv.h : own;   // k-slots j=0..3
        f16x4 q2 = xi ? own : rcv.h;   // k-slots j=4..7
        f16x8 t8;
#pragma unroll
        for (int j = 0; j < 4; ++j) {
          t8[j] = q1[j];
          t8[4 + j] = q2[j];
        }
        pb[2 * c + v] = t8;
      }

    // ---- O^T += V^T P^T (A = V^T rows dh, B = pb rows q) ----
    __builtin_amdgcn_s_setprio(1);
#pragma unroll
    for (int d = 0; d < 2; ++d) {
      int row = d * 32 + l31, s7 = l31 & 7;
      const f16* vbp = &Vb[cur][row * 64];
#pragma unroll
      for (int u = 0; u < 4; ++u) {
        f16x8 vf = *reinterpret_cast<const f16x8*>(vbp + (((2 * u + xi) ^ s7) * 8));
        O[d] = __builtin_amdgcn_mfma_f32_32x32x16_f16(vf, pb[u], O[d], 0, 0, 0);
      }
    }
    __builtin_amdgcn_s_setprio(0);
    __builtin_amdgcn_sched_barrier(0);
  }

  // ---- final sum: lanes l and l^32 hold disjoint kv-halves of q ----
  rsum += __shfl_xor(rsum, 32, 64);
  float inv = 1.0f / rsum;
  const int q = qw + l31;

  if (!split) {
    // ---- epilogue: ctx[b][q][h*64+dh]; reg 4g+e -> dh = d*32+8g+4xi+e ----
    f16* cp = ctx + ((size_t)b * 1024 + q) * 1024 + h * 64;
#pragma unroll
    for (int d = 0; d < 2; ++d)
#pragma unroll
      for (int g = 0; g < 4; ++g) {
        f16x4 v4;
#pragma unroll
        for (int e = 0; e < 4; ++e) v4[e] = (f16)(O[d][4 * g + e] * inv);
        *reinterpret_cast<f16x4*>(cp + d * 32 + 8 * g + 4 * xi) = v4;
      }
  } else {
    // ---- split epilogue: normalized partial O (f16) + LSE (f32) ----
    f16* op = opart + (size_t)kvh * 4194304 + ((size_t)bh * 1024 + q) * 64;
#pragma unroll
    for (int d = 0; d < 2; ++d)
#pragma unroll
      for (int g = 0; g < 4; ++g) {
        f16x4 v4;
#pragma unroll
        for (int e = 0; e < 4; ++e) v4[e] = (f16)(O[d][4 * g + e] * inv);
        *reinterpret_cast<f16x4*>(op + d * 32 + 8 * g + 4 * xi) = v4;
      }
    if (xi == 0)
      lsebuf[((size_t)kvh * 64 + bh) * 1024 + q] = mrun + __logf(rsum);
  }
}

// ---------------------------------------------------------------------------
// Split-KV combine: ctx = (w0*O0 + w1*O1)/(w0+w1), wi = exp(lse_i - max).
// 512K threads, f16x8 per thread (24 MB traffic).
// ---------------------------------------------------------------------------
__global__ __launch_bounds__(256) void k_combine(const f16* __restrict__ opart,
                                                 const float* __restrict__ lsebuf,
                                                 f16* __restrict__ ctx) {
  int idx = blockIdx.x * 256 + threadIdx.x;  // 0..524287
  int g8 = idx & 7, row = idx >> 3;          // row = bh*1024 + q
  int bh = row >> 10, q = row & 1023;
  float l0 = lsebuf[row], l1 = lsebuf[65536 + row];
  float L = fmaxf(l0, l1);
  float w0 = __expf(l0 - L), w1 = __expf(l1 - L);
  float inv = 1.0f / (w0 + w1);
  f16x8 a = *reinterpret_cast<const f16x8*>(opart + (size_t)row * 64 + g8 * 8);
  f16x8 c = *reinterpret_cast<const f16x8*>(opart + 4194304 + (size_t)row * 64 + g8 * 8);
  f16x8 o;
#pragma unroll
  for (int j = 0; j < 8; ++j)
    o[j] = (f16)((w0 * (float)a[j] + w1 * (float)c[j]) * inv);
  int b = bh >> 4, h = bh & 15;
  *reinterpret_cast<f16x8*>(ctx + ((size_t)b * 1024 + q) * 1024 + h * 64 + g8 * 8) = o;
}

// ---------------------------------------------------------------------------
extern "C" void kernel_launch(void* const* d_in, const int* in_sizes, int n_in,
                              void* d_out, int out_size, void* d_ws,
                              size_t ws_size, hipStream_t stream) {
  const float* input_ids = (const float*)d_in[0];
  const float* enc = (const float*)d_in[1];
  const float* bias = (const float*)d_in[2];
  const float* Wq = (const float*)d_in[3];
  const float* Wk = (const float*)d_in[4];
  const float* Wv = (const float*)d_in[5];
  const float* Wo = (const float*)d_in[6];

  char* ws = (char*)d_ws;
  const size_t MB = 1024 * 1024;
  const bool split = ws_size >= 51 * MB;
  f16* Xq  = (f16*)(ws + 0 * MB);   // 8 MB; dead after QKV-proj -> reused as ctx
  f16* Xkv = (f16*)(ws + 8 * MB);   // 8 MB; dead after qkv -> opart half0
  f16* Wqt = (f16*)(ws + 16 * MB);  // 2 MB each; Wqt|Wkt|Wvt contiguous; dead
  f16* Wkt = (f16*)(ws + 18 * MB);  //   after qkv -> opart half1 (16-24 MB)
  f16* Wvt = (f16*)(ws + 20 * MB);
  f16* Wot = (f16*)(ws + (split ? 48 * MB : 22 * MB));
  f16* qbuf = (f16*)(ws + 24 * MB); // 8 MB [bh][s][dh]; kbuf plane follows;
  f16* kbuf = (f16*)(ws + 32 * MB); // plane 2 = vtb [bh][dh][s]
  f16* vtb  = (f16*)(ws + 40 * MB);
  f16* opart = (f16*)(ws + 8 * MB); // 16 MB (2 halves of 8 MB), split only
  float* lsebuf = (float*)(ws + 50 * MB);  // 512 KB, split only
  f16* ctxb = Xq;   // [4096][1024]

  // merged cast + weight-transpose prep (one launch)
  k_prep<<<9216, 256, 0, stream>>>(input_ids, enc, Xq, Xkv, Wq, Wk, Wv, Wo,
                                   Wqt, Wkt, Wvt, Wot);

  // fused Q+K+V projection (Q/K planes swapped-operand, V transposed in epi)
  k_gemm_qkv<<<dim3(24, 32), 256, 0, stream>>>(Xq, Xkv, Wqt, qbuf);

  if (split) {
    k_attn<<<1024, 256, 0, stream>>>(qbuf, kbuf, vtb, bias, ctxb, opart,
                                     lsebuf, 1);
    k_combine<<<2048, 256, 0, stream>>>(opart, lsebuf, ctxb);
  } else {
    k_attn<<<512, 256, 0, stream>>>(qbuf, kbuf, vtb, bias, ctxb, opart,
                                    lsebuf, 0);
  }

  k_gemm_o<<<dim3(8, 64), 256, 0, stream>>>(ctxb, Wot, (float*)d_out, 4096, 1024, 1024);
}

// Round 24
// 136.723 us; speedup vs baseline: 1.0853x; 1.0853x over previous
//
#include <hip/hip_runtime.h>

typedef _Float16 f16;
typedef _Float16 f16x4 __attribute__((ext_vector_type(4)));
typedef _Float16 f16x8 __attribute__((ext_vector_type(8)));
typedef float f32x4 __attribute__((ext_vector_type(4)));
typedef float f32x16 __attribute__((ext_vector_type(16)));

// async global->LDS, 16B per lane; LDS dest = wave-uniform base + lane*16
#define LOADLDS16(gp, lp)                                                     \
  __builtin_amdgcn_global_load_lds(                                           \
      (const __attribute__((address_space(1))) void*)(gp),                    \
      (__attribute__((address_space(3))) void*)(lp), 16, 0, 0)

// ---------------------------------------------------------------------------
// Merged prep: blocks 0-8191 cast activations f32->f16 (float4 vectorized);
// blocks 8192-9215 cast+transpose the 4 weight matrices (64x64 LDS tiles).
// ---------------------------------------------------------------------------
__global__ __launch_bounds__(256) void k_prep(
    const float* __restrict__ xa, const float* __restrict__ xb,
    f16* __restrict__ ya, f16* __restrict__ yb, const float* __restrict__ w0,
    const float* __restrict__ w1, const float* __restrict__ w2,
    const float* __restrict__ w3, f16* __restrict__ o0, f16* __restrict__ o1,
    f16* __restrict__ o2, f16* __restrict__ o3) {
  __shared__ f16 T[64][72];
  const int tid = threadIdx.x;
  const int bid = blockIdx.x;
  if (bid < 8192) {
    int i = bid * 256 + tid;
    const float* x;
    f16* y;
    if (i < 1048576) {
      x = xa; y = ya;
    } else {
      x = xb; y = yb; i -= 1048576;
    }
    float4 v = reinterpret_cast<const float4*>(x)[i];
    f16x4 o;
    o[0] = (f16)v.x; o[1] = (f16)v.y; o[2] = (f16)v.z; o[3] = (f16)v.w;
    reinterpret_cast<f16x4*>(y)[i] = o;
    return;
  }
  const int bid2 = bid - 8192;
  const int z = bid2 >> 8, yb_ = (bid2 >> 4) & 15, xb_ = bid2 & 15;
  const float* W;
  f16* O;
  switch (z) {
    case 0: W = w0; O = o0; break;
    case 1: W = w1; O = o1; break;
    case 2: W = w2; O = o2; break;
    default: W = w3; O = o3; break;
  }
  const int r0 = yb_ * 64, c0 = xb_ * 64;
#pragma unroll
  for (int i = 0; i < 4; ++i) {
    int c = i * 256 + tid;
    int row = c >> 4, col = (c & 15) * 4;
    float4 v = *reinterpret_cast<const float4*>(W + (size_t)(r0 + row) * 1024 + c0 + col);
    T[col + 0][row] = (f16)v.x;
    T[col + 1][row] = (f16)v.y;
    T[col + 2][row] = (f16)v.z;
    T[col + 3][row] = (f16)v.w;
  }
  __syncthreads();
#pragma unroll
  for (int i = 0; i < 2; ++i) {
    int c = i * 256 + tid;
    int cc = c >> 3, ro = (c & 7) * 8;
    f16x8 v;
#pragma unroll
    for (int j = 0; j < 8; ++j) v[j] = T[cc][ro + j];
    *reinterpret_cast<f16x8*>(O + (size_t)(c0 + cc) * 1024 + r0 + ro) = v;
  }
}

// ---------------------------------------------------------------------------
// Fused QKV projection (round-18 v18, frozen): swizzled grid, swapped-operand
// Q/K epilogue (f16x4 stores), V written transposed.
// ---------------------------------------------------------------------------
__global__ __launch_bounds__(256) void k_gemm_qkv(const f16* __restrict__ Xq,
                                                  const f16* __restrict__ Xkv,
                                                  const f16* __restrict__ Bt,
                                                  f16* __restrict__ outp) {
  __shared__ f16 As[128 * 64];  // 16 KB
  __shared__ f16 Bs[128 * 64];  // 16 KB
  const int tid = threadIdx.x;
  const int w = tid >> 6, l = tid & 63;
  const int lr = l & 15, lq = l >> 4;
  const int flat = blockIdx.y * 24 + blockIdx.x;
  const int ord = (flat & 7) * 96 + (flat >> 3);
  const int m0 = (ord / 24) * 128, n0 = (ord % 24) * 128;
  const f16* A = (n0 < 1024) ? Xq : Xkv;
  const int wr = (w >> 1) * 64, wc = (w & 1) * 64;
  const int K = 1024;
  const bool vplane = (n0 >= 2048);
  f32x4 acc[4][4] = {};
  for (int kt = 0; kt < K; kt += 64) {
#pragma unroll
    for (int i = 0; i < 4; ++i) {
      int c = (i * 4 + w) * 64 + l;
      LOADLDS16(A + (size_t)(m0 + (c >> 3)) * K + kt + (c & 7) * 8,
                As + (size_t)(i * 4 + w) * 512);
      LOADLDS16(Bt + (size_t)(n0 + (c >> 3)) * K + kt + (c & 7) * 8,
                Bs + (size_t)(i * 4 + w) * 512);
    }
    __syncthreads();
#pragma unroll
    for (int kk = 0; kk < 2; ++kk) {
      f16x8 af[4], bf[4];
#pragma unroll
      for (int m = 0; m < 4; ++m)
        af[m] = *reinterpret_cast<const f16x8*>(As + (wr + m * 16 + lr) * 64 + kk * 32 + lq * 8);
#pragma unroll
      for (int n = 0; n < 4; ++n)
        bf[n] = *reinterpret_cast<const f16x8*>(Bs + (wc + n * 16 + lr) * 64 + kk * 32 + lq * 8);
      if (vplane) {
#pragma unroll
        for (int m = 0; m < 4; ++m)
#pragma unroll
          for (int n = 0; n < 4; ++n)
            acc[m][n] = __builtin_amdgcn_mfma_f32_16x16x32_f16(af[m], bf[n], acc[m][n], 0, 0, 0);
      } else {
#pragma unroll
        for (int m = 0; m < 4; ++m)
#pragma unroll
          for (int n = 0; n < 4; ++n)
            acc[m][n] = __builtin_amdgcn_mfma_f32_16x16x32_f16(bf[n], af[m], acc[m][n], 0, 0, 0);
      }
    }
    __syncthreads();
  }
  if (vplane) {
#pragma unroll
    for (int m = 0; m < 4; ++m)
#pragma unroll
      for (int n = 0; n < 4; ++n) {
        int col = n0 + wc + n * 16 + lr;
        int row0 = m0 + wr + m * 16 + lq * 4;
        int b = row0 >> 10, s0 = row0 & 1023;
        int cc = col & 1023;
        int h = cc >> 6, dh = cc & 63;
        f16x4 v4;
#pragma unroll
        for (int r = 0; r < 4; ++r) v4[r] = (f16)acc[m][n][r];
        *reinterpret_cast<f16x4*>(
            outp + (size_t)2 * 4194304 +
            ((size_t)(b * 16 + h)) * 65536 + (size_t)dh * 1024 + s0) = v4;
      }
  } else {
#pragma unroll
    for (int m = 0; m < 4; ++m)
#pragma unroll
      for (int n = 0; n < 4; ++n) {
        int row0 = m0 + wr + m * 16 + lr;
        int col0 = n0 + wc + n * 16 + lq * 4;
        int b = row0 >> 10, sidx = row0 & 1023;
        int plane = col0 >> 10, cc = col0 & 1023;
        int h = cc >> 6, dh0 = cc & 63;
        f16x4 v4;
#pragma unroll
        for (int r = 0; r < 4; ++r) v4[r] = (f16)acc[m][n][r];
        *reinterpret_cast<f16x4*>(
            outp + (size_t)plane * 4194304 +
            (((size_t)(b * 16 + h)) * 1024 + sidx) * 64 + dh0) = v4;
      }
  }
}

// ---------------------------------------------------------------------------
// Output GEMM (round-18 v18, frozen): swizzled grid, BM=64 BN=128.
// ---------------------------------------------------------------------------
__global__ __launch_bounds__(256) void k_gemm_o(const f16* __restrict__ A,
                                                const f16* __restrict__ Bt,
                                                float* __restrict__ out, int M,
                                                int N, int K) {
  __shared__ f16 As[64 * 64];
  __shared__ f16 Bs[128 * 64];
  const int tid = threadIdx.x;
  const int w = tid >> 6, l = tid & 63;
  const int lr = l & 15, lq = l >> 4;
  const int flat = blockIdx.y * 8 + blockIdx.x;
  const int ord = (flat & 7) * 64 + (flat >> 3);
  const int m0 = (ord >> 3) * 64, n0 = (ord & 7) * 128;
  const int wr = (w >> 1) * 32, wc = (w & 1) * 64;
  f32x4 acc[2][4] = {};
  for (int kt = 0; kt < K; kt += 64) {
#pragma unroll
    for (int i = 0; i < 2; ++i) {
      int c = (i * 4 + w) * 64 + l;
      LOADLDS16(A + (size_t)(m0 + (c >> 3)) * K + kt + (c & 7) * 8,
                As + (size_t)(i * 4 + w) * 512);
    }
#pragma unroll
    for (int i = 0; i < 4; ++i) {
      int c = (i * 4 + w) * 64 + l;
      LOADLDS16(Bt + (size_t)(n0 + (c >> 3)) * K + kt + (c & 7) * 8,
                Bs + (size_t)(i * 4 + w) * 512);
    }
    __syncthreads();
#pragma unroll
    for (int kk = 0; kk < 2; ++kk) {
      f16x8 af[2], bf[4];
#pragma unroll
      for (int m = 0; m < 2; ++m)
        af[m] = *reinterpret_cast<const f16x8*>(As + (wr + m * 16 + lr) * 64 + kk * 32 + lq * 8);
#pragma unroll
      for (int n = 0; n < 4; ++n)
        bf[n] = *reinterpret_cast<const f16x8*>(Bs + (wc + n * 16 + lr) * 64 + kk * 32 + lq * 8);
#pragma unroll
      for (int m = 0; m < 2; ++m)
#pragma unroll
        for (int n = 0; n < 4; ++n)
          acc[m][n] = __builtin_amdgcn_mfma_f32_16x16x32_f16(af[m], bf[n], acc[m][n], 0, 0, 0);
    }
    __syncthreads();
  }
#pragma unroll
  for (int m = 0; m < 2; ++m)
#pragma unroll
    for (int n = 0; n < 4; ++n)
#pragma unroll
      for (int r = 0; r < 4; ++r) {
        int row = m0 + wr + m * 16 + lq * 4 + r;
        int col = n0 + wc + n * 16 + lr;
        out[(size_t)row * N + col] = acc[m][n][r];
      }
}

// ---------------------------------------------------------------------------
// Fused flash attention (T5), v19 (BEST MEASURED, final): 32x32x16 core,
// 4 waves x 32 q-rows (QBLK=128), KVBLK=64, grid 512 (2 blocks/CU).
// Swapped QK (S^T = mfma(K,Q,bias-in-regs)), defer-max, in-register P via
// lane^32 quad exchange, counted-vmcnt 2-phase DMA pipeline, FIFO-ordered
// bias loads (bias older than stage(t+1) -> implicit wait drains bias only).
// ---------------------------------------------------------------------------
__global__ __launch_bounds__(256, 2) void k_attn(const f16* __restrict__ qb,
                                                 const f16* __restrict__ kb,
                                                 const f16* __restrict__ vtb,
                                                 const float* __restrict__ bias,
                                                 f16* __restrict__ ctx) {
  const int bid = blockIdx.x;
  const int ord = (bid & 7) * 64 + (bid >> 3);  // XCD-chunked: 2 heads/XCD
  const int h = ord >> 5, b = (ord >> 3) & 3, qt = ord & 7;  // qt innermost
  const int bh = b * 16 + h;
  const int q0 = qt * 128;
  const int tid = threadIdx.x, w = tid >> 6, l = tid & 63;
  const int l31 = l & 31, xi = l >> 5;
  const int qw = q0 + w * 32;

  __shared__ f16 Kb[2][4096];  // [kv=64][dh=64], granule swz g^(row&7)
  __shared__ f16 Vb[2][4096];  // [dh=64][kv=64], granule swz g^(row&7)

  // Q B-fragments: Q[q = qw + l31][dh = s*16 + xi*8 .. +7], s = 0..3
  const f16* qp = qb + ((size_t)bh * 1024 + qw + l31) * 64 + xi * 8;
  f16x8 qf[4];
#pragma unroll
  for (int s = 0; s < 4; ++s)
    qf[s] = *reinterpret_cast<const f16x8*>(qp + s * 16);

  f32x16 O[2] = {};
  float mrun = -3.0e38f, rsum = 0.f;  // per-lane; q-row = qw + l31

  const f16* kbase = kb + (size_t)bh * 65536;
  const f16* vbase = vtb + (size_t)bh * 65536;
  // bias: S[c][4g+e] needs bias[q][t*64 + c*32 + 8g + 4*xi + e]
  const float* bq =
      bias + ((size_t)h * 1024 + qw + l31) * 1024 + 4 * xi;

  // DMA staging: 512 chunks of 16B per tile.
  auto stage = [&](int t, int nxt) {
#pragma unroll
    for (int i = 0; i < 2; ++i) {
      int c = (i * 4 + w) * 64 + l;
      int row = c >> 3, g = (c & 7) ^ (row & 7);
      LOADLDS16(kbase + (size_t)(t * 64 + row) * 64 + g * 8,
                &Kb[nxt][(i * 4 + w) * 512]);
      LOADLDS16(vbase + (size_t)row * 1024 + t * 64 + g * 8,
                &Vb[nxt][(i * 4 + w) * 512]);
    }
  };

  stage(0, 0);

#pragma unroll 1
  for (int t = 0; t < 16; ++t) {
    const int cur = t & 1;
    __builtin_amdgcn_s_barrier();
    // ---- bias loads FIRST (older than stage(t+1) in the VM queue) ----
    f32x4 bf[2][4];
#pragma unroll
    for (int c = 0; c < 2; ++c)
#pragma unroll
      for (int g = 0; g < 4; ++g)
        bf[c][g] = *reinterpret_cast<const f32x4*>(bq + t * 64 + c * 32 + 8 * g);
    __builtin_amdgcn_sched_barrier(0);
    if (t < 15) stage(t + 1, cur ^ 1);
    __builtin_amdgcn_sched_barrier(0);
    // drain ONLY stage(t): outstanding = 4(stage t) + 8(bias) + 4(stage t+1)
    if (t < 15) {
      asm volatile("s_waitcnt vmcnt(12)" ::: "memory");
    } else {
      asm volatile("s_waitcnt vmcnt(8)" ::: "memory");
    }
    __builtin_amdgcn_sched_barrier(0);

    // ---- S^T = K Q^T + bias  (S[c]: col q, rows kv = c*32 + pattern) ----
    f32x16 S[2];
#pragma unroll
    for (int c = 0; c < 2; ++c) {
#pragma unroll
      for (int g = 0; g < 4; ++g)
#pragma unroll
        for (int e = 0; e < 4; ++e) S[c][4 * g + e] = bf[c][g][e];
    }
    __builtin_amdgcn_s_setprio(1);
#pragma unroll
    for (int c = 0; c < 2; ++c) {
      int row = c * 32 + l31, s7 = l31 & 7;
      const f16* kbp = &Kb[cur][row * 64];
#pragma unroll
      for (int s = 0; s < 4; ++s) {
        f16x8 kf = *reinterpret_cast<const f16x8*>(kbp + (((2 * s + xi) ^ s7) * 8));
        S[c] = __builtin_amdgcn_mfma_f32_32x32x16_f16(kf, qf[s], S[c], 0, 0, 0);
      }
    }
    __builtin_amdgcn_s_setprio(0);

    // ---- defer-max (T13): all 32 S-values belong to one q-row ----
    float tmax = -3.0e38f;
#pragma unroll
    for (int c = 0; c < 2; ++c)
#pragma unroll
      for (int r = 0; r < 16; ++r) tmax = fmaxf(tmax, S[c][r]);
    if (!__all(tmax <= mrun + 8.0f)) {
      tmax = fmaxf(tmax, __shfl_xor(tmax, 32, 64));
      float mnew = fmaxf(mrun, tmax);
      float sc = __expf(mrun - mnew);  // identical in lanes l, l^32
      mrun = mnew;
      rsum *= sc;
#pragma unroll
      for (int d = 0; d < 2; ++d)
#pragma unroll
        for (int r = 0; r < 16; ++r) O[d][r] *= sc;
    }

    // ---- P = exp(S - m); per-lane rsum; pack quads ----
    f16x4 qd[2][4];
#pragma unroll
    for (int c = 0; c < 2; ++c)
#pragma unroll
      for (int g = 0; g < 4; ++g) {
        f32x4 p;
#pragma unroll
        for (int e = 0; e < 4; ++e) p[e] = __expf(S[c][4 * g + e] - mrun);
        rsum += (p[0] + p[1]) + (p[2] + p[3]);
        f16x4 ph = {(f16)p[0], (f16)p[1], (f16)p[2], (f16)p[3]};
        qd[c][g] = ph;
      }

    // ---- quad exchange with lane^32: build pb[u], u = 2c+v ----
    f16x8 pb[4];
#pragma unroll
    for (int c = 0; c < 2; ++c)
#pragma unroll
      for (int v = 0; v < 2; ++v) {
        union { f16x4 h; unsigned int u[2]; } snd, rcv;
        snd.h = xi ? qd[c][2 * v] : qd[c][2 * v + 1];
        rcv.u[0] = __shfl_xor(snd.u[0], 32, 64);
        rcv.u[1] = __shfl_xor(snd.u[1], 32, 64);
        f16x4 own = xi ? qd[c][2 * v + 1] : qd[c][2 * v];
        f16x4 q1 = xi ? rcv.h : own;   // k-slots j=0..3
        f16x4 q2 = xi ? own : rcv.h;   // k-slots j=4..7
        f16x8 t8;
#pragma unroll
        for (int j = 0; j < 4; ++j) {
          t8[j] = q1[j];
          t8[4 + j] = q2[j];
        }
        pb[2 * c + v] = t8;
      }

    // ---- O^T += V^T P^T (A = V^T rows dh, B = pb rows q) ----
    __builtin_amdgcn_s_setprio(1);
#pragma unroll
    for (int d = 0; d < 2; ++d) {
      int row = d * 32 + l31, s7 = l31 & 7;
      const f16* vbp = &Vb[cur][row * 64];
#pragma unroll
      for (int u = 0; u < 4; ++u) {
        f16x8 vf = *reinterpret_cast<const f16x8*>(vbp + (((2 * u + xi) ^ s7) * 8));
        O[d] = __builtin_amdgcn_mfma_f32_32x32x16_f16(vf, pb[u], O[d], 0, 0, 0);
      }
    }
    __builtin_amdgcn_s_setprio(0);
    __builtin_amdgcn_sched_barrier(0);
  }

  // ---- final sum: lanes l and l^32 hold disjoint kv-halves of q ----
  rsum += __shfl_xor(rsum, 32, 64);
  float inv = 1.0f / rsum;

  // ---- epilogue: ctx[b][q][h*64+dh]; O[d] reg 4g+e -> dh = d*32+8g+4xi+e ----
  const int q = qw + l31;
  f16* cp = ctx + ((size_t)b * 1024 + q) * 1024 + h * 64;
#pragma unroll
  for (int d = 0; d < 2; ++d)
#pragma unroll
    for (int g = 0; g < 4; ++g) {
      f16x4 v4;
#pragma unroll
      for (int e = 0; e < 4; ++e) v4[e] = (f16)(O[d][4 * g + e] * inv);
      *reinterpret_cast<f16x4*>(cp + d * 32 + 8 * g + 4 * xi) = v4;
    }
}

// ---------------------------------------------------------------------------
extern "C" void kernel_launch(void* const* d_in, const int* in_sizes, int n_in,
                              void* d_out, int out_size, void* d_ws,
                              size_t ws_size, hipStream_t stream) {
  const float* input_ids = (const float*)d_in[0];
  const float* enc = (const float*)d_in[1];
  const float* bias = (const float*)d_in[2];
  const float* Wq = (const float*)d_in[3];
  const float* Wk = (const float*)d_in[4];
  const float* Wv = (const float*)d_in[5];
  const float* Wo = (const float*)d_in[6];

  char* ws = (char*)d_ws;
  const size_t MB = 1024 * 1024;
  f16* Xq  = (f16*)(ws + 0 * MB);   // 8 MB; dead after QKV-proj -> reused as ctx
  f16* Xkv = (f16*)(ws + 8 * MB);   // 8 MB (GEMM A input)
  f16* Wqt = (f16*)(ws + 16 * MB);  // 2 MB each; Wqt|Wkt|Wvt contiguous = [3072][1024]
  f16* Wkt = (f16*)(ws + 18 * MB);
  f16* Wvt = (f16*)(ws + 20 * MB);
  f16* Wot = (f16*)(ws + 22 * MB);
  f16* qbuf = (f16*)(ws + 24 * MB); // 8 MB [bh][s][dh]; kbuf plane follows;
  f16* kbuf = (f16*)(ws + 32 * MB); // plane 2 = vtb [bh][dh][s] (transposed in epi)
  f16* vtb  = (f16*)(ws + 40 * MB);
  f16* ctxb = Xq;   // [4096][1024]

  // merged cast + weight-transpose prep (one launch)
  k_prep<<<9216, 256, 0, stream>>>(input_ids, enc, Xq, Xkv, Wq, Wk, Wv, Wo,
                                   Wqt, Wkt, Wvt, Wot);

  // fused Q+K+V projection (Q/K planes swapped-operand, V transposed in epi)
  k_gemm_qkv<<<dim3(24, 32), 256, 0, stream>>>(Xq, Xkv, Wqt, qbuf);

  k_attn<<<512, 256, 0, stream>>>(qbuf, kbuf, vtb, bias, ctxb);

  k_gemm_o<<<dim3(8, 64), 256, 0, stream>>>(ctxb, Wot, (float*)d_out, 4096, 1024, 1024);
}